// Round 1
// baseline (75.071 us; speedup 1.0000x reference)
//
#include <hip/hip_runtime.h>

// Problem constants (from reference): repr [512, 768] fp32, GT [512] int32 (positions permutation),
// out = sum_{i<j} || relu(r_i - r_j) ||_2  with r = repr[GT].
#define MM 512
#define NN 768
#define BI 8     // i-rows per block
#define BJ 32    // j-rows per block
#define NC 128   // N-chunk staged per iteration
#define SJ 132   // padded LDS row stride in floats (132*4=528B, 16B aligned, breaks pow2 bank stride)

// Grid: tiles (ti in 0..63 over i, tj in 0..15 over j), alive iff min_i < max_j
// i.e. ti <= 4*tj+3  -> count per tj = 4*tj+4, total = 544 blocks.
// cum(tj) = 2*tj*(tj+1).

__global__ __launch_bounds__(256, 4)
void ClipPairWiseLossAll_kernel(const float* __restrict__ repr,
                                const int* __restrict__ GT,
                                float* __restrict__ out) {
    __shared__ float ldsJ[BJ * SJ];
    __shared__ float ldsI[BI * SJ];
    __shared__ float red[4];

    const int b = blockIdx.x;
    int tj = 0;
    while (2 * (tj + 1) * (tj + 2) <= b) tj++;   // <=16 cheap scalar iters
    const int ti = b - 2 * tj * (tj + 1);
    const int ibase = ti * BI;
    const int jbase = tj * BJ;

    const int t    = threadIdx.x;
    const int lane = t & 63;
    const int w    = t >> 6;          // wave id 0..3
    const int jl   = lane & 31;       // j within tile
    const int il   = (w << 1) | (lane >> 5);   // i within tile 0..7

    const int gi = ibase + il;        // position index (mask uses positions, not GT values)
    const int gj = jbase + jl;

    // staging mapping: 32 lanes sweep a 128-float row chunk as float4s
    const int sg = t & 31;            // float4 index within chunk
    const int sr = t >> 5;            // row 0..7

    // gather row indices once (chunk-invariant)
    int growJ[4];
#pragma unroll
    for (int it = 0; it < 4; it++) growJ[it] = GT[jbase + sr + (it << 3)];
    const int growI = GT[ibase + sr];

    float acc0 = 0.f, acc1 = 0.f, acc2 = 0.f, acc3 = 0.f;

    for (int c0 = 0; c0 < NN; c0 += NC) {
        // stage 32 J-rows (rows sr, sr+8, sr+16, sr+24)
#pragma unroll
        for (int it = 0; it < 4; it++) {
            const int r = sr + (it << 3);
            const float4 v = *(const float4*)(repr + (size_t)growJ[it] * NN + c0 + (sg << 2));
            *(float4*)(ldsJ + r * SJ + (sg << 2)) = v;
        }
        // stage 8 I-rows
        {
            const float4 v = *(const float4*)(repr + (size_t)growI * NN + c0 + (sg << 2));
            *(float4*)(ldsI + sr * SJ + (sg << 2)) = v;
        }
        __syncthreads();

        const float* rjp = ldsJ + jl * SJ;
        const float* rip = ldsI + il * SJ;
#pragma unroll 8
        for (int g = 0; g < NC / 4; g++) {
            const float4 rj = *(const float4*)(rjp + (g << 2));
            const float4 ri = *(const float4*)(rip + (g << 2));
            const float d0 = fmaxf(ri.x - rj.x, 0.f);
            const float d1 = fmaxf(ri.y - rj.y, 0.f);
            const float d2 = fmaxf(ri.z - rj.z, 0.f);
            const float d3 = fmaxf(ri.w - rj.w, 0.f);
            acc0 = fmaf(d0, d0, acc0);
            acc1 = fmaf(d1, d1, acc1);
            acc2 = fmaf(d2, d2, acc2);
            acc3 = fmaf(d3, d3, acc3);
        }
        __syncthreads();
    }

    // epilogue: sqrt + mask (acc sums are >=0, sqrt safe to compute speculatively)
    float val = (gi < gj) ? sqrtf(acc0 + acc1 + acc2 + acc3) : 0.f;

    // wave reduction (64 lanes)
#pragma unroll
    for (int off = 32; off > 0; off >>= 1)
        val += __shfl_down(val, off, 64);
    if (lane == 0) red[w] = val;
    __syncthreads();
    if (t == 0) {
        atomicAdd(out, red[0] + red[1] + red[2] + red[3]);
    }
}

extern "C" void kernel_launch(void* const* d_in, const int* in_sizes, int n_in,
                              void* d_out, int out_size, void* d_ws, size_t ws_size,
                              hipStream_t stream) {
    const float* repr = (const float*)d_in[0];
    const int*   GT   = (const int*)d_in[1];
    float* out = (float*)d_out;

    // d_out is poisoned to 0xAA before every timed replay -> must zero it ourselves.
    hipMemsetAsync(out, 0, sizeof(float) * (size_t)out_size, stream);

    ClipPairWiseLossAll_kernel<<<544, 256, 0, stream>>>(repr, GT, out);
}